// Round 7
// baseline (61.087 us; speedup 1.0000x reference)
//
#include <hip/hip_runtime.h>
#include <hip/hip_bf16.h>
#include <stdint.h>

typedef short bf16x8 __attribute__((ext_vector_type(8)));
typedef float f32x4  __attribute__((ext_vector_type(4)));

__device__ __forceinline__ ushort f2b(float f) {
  __hip_bfloat16 t = __float2bfloat16(f);
  return *reinterpret_cast<ushort*>(&t);
}
__device__ __forceinline__ bf16x8 pack8(float4 a, float4 b) {
  bf16x8 r;
  r[0]=(short)f2b(a.x); r[1]=(short)f2b(a.y); r[2]=(short)f2b(a.z); r[3]=(short)f2b(a.w);
  r[4]=(short)f2b(b.x); r[5]=(short)f2b(b.y); r[6]=(short)f2b(b.z); r[7]=(short)f2b(b.w);
  return r;
}

// ---------------- Phase 0: repack W1 -> bf16 B-fragment blob ----------------
__global__ void repack_W1(const float* __restrict__ W1, int4* __restrict__ blob) {
  const int tid = blockIdx.x * 256 + threadIdx.x;     // 0..4095
  const int l15  = tid & 15;
  const int lg   = (tid >> 4) & 3;
  const int kk   = (tid >> 6) & 3;
  const int nt   = (tid >> 8) & 7;
  const int half = (tid >> 11) & 1;
  const float* wp = W1 + (size_t)(nt * 16 + l15) * 256 + half * 128 + kk * 32 + lg * 8;
  const float4 fa = *(const float4*)wp;
  const float4 fb = *(const float4*)(wp + 4);
  bf16x8 r = pack8(fa, fb);
  blob[tid] = *reinterpret_cast<int4*>(&r);
}

// ---------------- Phase 1: u/v -> biased uint8 + per-half scales; 2-deep pipeline ----------
// Double-buffered 16-node bf16 LDS tile; ONE barrier per iteration. Steady state:
//   issue loads(t+2) -> ds_write(t+1 -> buf^1, loads issued last iter: no vmcnt stall)
//   -> compute+quant(t from buf) -> barrier -> rotate.
// Wave w owns out-cols [64w,64w+64): half=w>>1 (u/v), hw=w&1. Byte layout per node:
// byte pos l15*8 + hw*4 + ntl <-> col hw*64 + ntl*16 + l15 (j<4 scale .x, j>=4 .y).
__global__ __launch_bounds__(256, 3) void node_uv(
    const float* __restrict__ h, const int4* __restrict__ blob,
    const float* __restrict__ b1,
    uint8_t* __restrict__ u8, uint8_t* __restrict__ v8,
    float* __restrict__ su, float* __restrict__ sv,   // [Nn][2]
    int Nn, int NT, int nblocks, int niter)
{
  __shared__ ushort As[2][2048];        // 2 x (16 rows x 128 cols bf16), XOR-swizzled; 8 KiB

  const int t0   = threadIdx.x;
  const int w    = t0 >> 6;
  const int l    = t0 & 63;
  const int l15  = l & 15;
  const int lg   = l >> 4;
  const int half = w >> 1;
  const int hw   = w & 1;

  bf16x8 bfrag[4][4];
#pragma unroll
  for (int ntl = 0; ntl < 4; ++ntl)
#pragma unroll
    for (int kk = 0; kk < 4; ++kk) {
      int4 x = blob[((half * 8 + hw * 4 + ntl) * 4 + kk) * 64 + l];
      bfrag[ntl][kk] = *reinterpret_cast<bf16x8*>(&x);
    }

  float b1r[4];
#pragma unroll
  for (int ntl = 0; ntl < 4; ++ntl)
    b1r[ntl] = half ? 0.f : b1[hw * 64 + ntl * 16 + l15];

  uint8_t* __restrict__ outp = half ? v8 : u8;
  float*   __restrict__ outs = half ? sv : su;

  const float4* h4 = (const float4*)h;

#define LOADT(T, g)                                            \
  {                                                            \
    const size_t hb = (size_t)(T) * 512;                       \
    _Pragma("unroll")                                          \
    for (int k = 0; k < 2; ++k) {                              \
      const int i = k * 256 + t0;                              \
      const int gr = (T) * 16 + (i >> 5);                      \
      (g)[k] = h4[gr < Nn ? hb + i : 0];                       \
    }                                                          \
  }

#define STORET(b, g)                                           \
  {                                                            \
    _Pragma("unroll")                                          \
    for (int k = 0; k < 2; ++k) {                              \
      const int i = k * 256 + t0, row = i >> 5, c = i & 31;    \
      ushort4 o;                                               \
      o.x = f2b((g)[k].x); o.y = f2b((g)[k].y);                \
      o.z = f2b((g)[k].z); o.w = f2b((g)[k].w);                \
      *(ushort4*)(&As[b][row * 128 + (((c >> 1) ^ (row & 7)) << 3) + (c & 1) * 4]) = o; \
    }                                                          \
  }

  int tc = blockIdx.x;
  int tn = tc + nblocks;
  float4 gC[2], gN[2], gNN[2];
  LOADT(tc, gC);
  LOADT(tn, gN);
  STORET(0, gC);
  __syncthreads();
  int cur = 0;

  for (int it = 0; it < niter; ++it) {
    const int tnn = tn + nblocks;
    LOADT(tnn, gNN);          // 2-ahead, stays in flight across the barrier
    STORET(cur ^ 1, gN);      // t+1 -> other buffer; its loads are a full iter old

    if (tc < NT) {
      f32x4 acc[4];
#pragma unroll
      for (int ntl = 0; ntl < 4; ++ntl) acc[ntl] = (f32x4){0.f, 0.f, 0.f, 0.f};

#pragma unroll
      for (int kk = 0; kk < 4; ++kk) {
        const int slot = (kk * 4 + lg) ^ (l15 & 7);
        int4 av = *(const int4*)(&As[cur][l15 * 128 + slot * 8]);
        const bf16x8 a = *reinterpret_cast<bf16x8*>(&av);
#pragma unroll
        for (int ntl = 0; ntl < 4; ++ntl)
          acc[ntl] = __builtin_amdgcn_mfma_f32_16x16x32_bf16(a, bfrag[ntl][kk], acc[ntl], 0, 0, 0);
      }

      const int n0 = tc * 16;
#pragma unroll
      for (int r = 0; r < 4; ++r) {
        float vals[4];
        float m = 1e-30f;
#pragma unroll
        for (int ntl = 0; ntl < 4; ++ntl) {
          const float x = acc[ntl][r] + b1r[ntl];
          vals[ntl] = x;
          m = fmaxf(m, fabsf(x));
        }
        m = fmaxf(m, __shfl_xor(m, 1));
        m = fmaxf(m, __shfl_xor(m, 2));
        m = fmaxf(m, __shfl_xor(m, 4));
        m = fmaxf(m, __shfl_xor(m, 8));
        const float inv = 127.0f * __builtin_amdgcn_rcpf(m);
        uint32_t pk = 0;
#pragma unroll
        for (int j = 0; j < 4; ++j) {
          const int q = (int)rintf(vals[j] * inv) + 128;        // 1..255
          pk |= (uint32_t)q << (8 * j);
        }
        const int node = n0 + lg * 4 + r;
        if (node < Nn) {
          *(uint32_t*)(outp + (size_t)node * 128 + l15 * 8 + hw * 4) = pk;
          if (l15 == 0) outs[node * 2 + hw] = m * (1.0f / 127.0f);
        }
      }
    }

    __syncthreads();          // buf[cur] reads done + buf[cur^1] writes visible
    tc = tn; tn = tnn;
    gN[0] = gNN[0]; gN[1] = gNN[1];
    cur ^= 1;
  }
#undef LOADT
#undef STORET
}

// ---------------- Phase 2: score[e] = w2 . relu(s_u*(qu-128) + s_v*(qv-128)) + b2 ----------
// 16-lane group per edge, 8 edges per group-iteration (deep ILP on the random gathers).
__global__ __launch_bounds__(256) void edge_score_i8(
    const uint8_t* __restrict__ u8, const uint8_t* __restrict__ v8,
    const float* __restrict__ su, const float* __restrict__ sv,  // [Nn][2]
    const int* __restrict__ src, const int* __restrict__ dst,
    const float* __restrict__ w2, const float* __restrict__ b2p,
    float* __restrict__ out, int E)
{
  const int t  = threadIdx.x;
  const int l  = t & 63;
  const int q  = l & 15;
  const int lg = l >> 4;

  float w2r[8];
#pragma unroll
  for (int j = 0; j < 8; ++j) w2r[j] = w2[j * 16 + q];
  const float b2 = b2p[0];

  const int gw = blockIdx.x * 4 + (t >> 6);
  const int TW = gridDim.x * 4;
  const float2* su2 = (const float2*)su;
  const float2* sv2 = (const float2*)sv;

  for (int base = gw * 32; base < E; base += TW * 32) {
    int e[8]; bool ok[8];
    uint2 ug[8], vg[8];
    float2 ss[8], sd[8];
#pragma unroll
    for (int i = 0; i < 8; ++i) {
      e[i]  = base + i * 4 + lg;
      ok[i] = e[i] < E;
      const int eS = ok[i] ? e[i] : 0;
      const int s = src[eS];
      const int d = dst[eS];
      ug[i] = *(const uint2*)(u8 + (size_t)s * 128 + q * 8);
      vg[i] = *(const uint2*)(v8 + (size_t)d * 128 + q * 8);
      ss[i] = su2[s];
      sd[i] = sv2[d];
    }
#pragma unroll
    for (int i = 0; i < 8; ++i) {
      const uint32_t ux = ug[i].x, uy = ug[i].y;
      const uint32_t vx = vg[i].x, vy = vg[i].y;
      const float bse0 = -128.0f * (ss[i].x + sd[i].x);
      const float bse1 = -128.0f * (ss[i].y + sd[i].y);
      float acc = 0.f;
#pragma unroll
      for (int j = 0; j < 4; ++j) {
        const float cu = (float)((ux >> (8 * j)) & 0xffu);   // v_cvt_f32_ubyteN
        const float cv = (float)((vx >> (8 * j)) & 0xffu);
        float x = fmaf(cu, ss[i].x, fmaf(cv, sd[i].x, bse0));
        x = fmaxf(x, 0.f);
        acc = fmaf(x, w2r[j], acc);
      }
#pragma unroll
      for (int j = 0; j < 4; ++j) {
        const float cu = (float)((uy >> (8 * j)) & 0xffu);
        const float cv = (float)((vy >> (8 * j)) & 0xffu);
        float x = fmaf(cu, ss[i].y, fmaf(cv, sd[i].y, bse1));
        x = fmaxf(x, 0.f);
        acc = fmaf(x, w2r[4 + j], acc);
      }
      acc += __shfl_xor(acc, 1);
      acc += __shfl_xor(acc, 2);
      acc += __shfl_xor(acc, 4);
      acc += __shfl_xor(acc, 8);
      if (q == 0 && ok[i]) out[e[i]] = acc + b2;
    }
  }
}

extern "C" void kernel_launch(void* const* d_in, const int* in_sizes, int n_in,
                              void* d_out, int out_size, void* d_ws, size_t ws_size,
                              hipStream_t stream) {
  const float* h   = (const float*)d_in[0];
  const int*   src = (const int*)d_in[1];
  const int*   dst = (const int*)d_in[2];
  const float* W1  = (const float*)d_in[3];
  const float* b1  = (const float*)d_in[4];
  const float* w2  = (const float*)d_in[5];
  const float* b2  = (const float*)d_in[6];
  float* out = (float*)d_out;

  const int nh = in_sizes[0];
  const int Nn = nh / 128;
  const int E  = in_sizes[1];

  uint8_t* ws = (uint8_t*)d_ws;
  int4*  blob = (int4*)ws;                                          // 64 KiB
  size_t off  = 65536;
  float* su   = (float*)(ws + off);  off += (size_t)Nn * 8;
  off = (off + 511) & ~(size_t)511;
  float* sv   = (float*)(ws + off);  off += (size_t)Nn * 8;
  off = (off + 511) & ~(size_t)511;
  uint8_t* u8 = ws + off;            off += (size_t)Nn * 128;
  uint8_t* v8 = ws + off;

  hipLaunchKernelGGL(repack_W1, dim3(16), dim3(256), 0, stream, W1, blob);

  const int NT      = (Nn + 15) / 16;
  const int nblocks = 768;                     // 3 blocks/CU resident (persistent)
  const int niter   = (NT + nblocks - 1) / nblocks;
  hipLaunchKernelGGL(node_uv, dim3(nblocks), dim3(256), 0, stream,
                     h, blob, b1, u8, v8, su, sv, Nn, NT, nblocks, niter);

  hipLaunchKernelGGL(edge_score_i8, dim3(2048), dim3(256), 0, stream,
                     u8, v8, su, sv, src, dst, w2, b2, out, E);
}

// Round 8
// 59.274 us; speedup vs baseline: 1.0306x; 1.0306x over previous
//
#include <hip/hip_runtime.h>
#include <hip/hip_bf16.h>
#include <stdint.h>

typedef short bf16x8 __attribute__((ext_vector_type(8)));
typedef float f32x4  __attribute__((ext_vector_type(4)));

__device__ __forceinline__ ushort f2b(float f) {
  __hip_bfloat16 t = __float2bfloat16(f);
  return *reinterpret_cast<ushort*>(&t);
}
__device__ __forceinline__ bf16x8 pack8(float4 a, float4 b) {
  bf16x8 r;
  r[0]=(short)f2b(a.x); r[1]=(short)f2b(a.y); r[2]=(short)f2b(a.z); r[3]=(short)f2b(a.w);
  r[4]=(short)f2b(b.x); r[5]=(short)f2b(b.y); r[6]=(short)f2b(b.z); r[7]=(short)f2b(b.w);
  return r;
}

// ---------------- Phase 0: repack W1 -> bf16 B-fragment blob ----------------
__global__ void repack_W1(const float* __restrict__ W1, int4* __restrict__ blob) {
  const int tid = blockIdx.x * 256 + threadIdx.x;     // 0..4095
  const int l15  = tid & 15;
  const int lg   = (tid >> 4) & 3;
  const int kk   = (tid >> 6) & 3;
  const int nt   = (tid >> 8) & 7;
  const int half = (tid >> 11) & 1;
  const float* wp = W1 + (size_t)(nt * 16 + l15) * 256 + half * 128 + kk * 32 + lg * 8;
  const float4 fa = *(const float4*)wp;
  const float4 fb = *(const float4*)(wp + 4);
  bf16x8 r = pack8(fa, fb);
  blob[tid] = *reinterpret_cast<int4*>(&r);
}

// Raw barrier: LDS-visibility only. Does NOT drain vmcnt -> global prefetch
// loads stay in flight across the barrier (T4 counted-vmcnt pattern; the
// compiler's automatic dependence waitcnt on the prefetch registers is the
// counted vmcnt(N)).
__device__ __forceinline__ void lds_barrier() {
  asm volatile("s_waitcnt lgkmcnt(0)" ::: "memory");
  __builtin_amdgcn_sched_barrier(0);
  __builtin_amdgcn_s_barrier();
  __builtin_amdgcn_sched_barrier(0);
}

// ---------------- Phase 1: u/v -> biased uint8 + per-half scales; 2-deep pipeline ----------
// Double-buffered 16-node bf16 LDS tile; ONE raw barrier per iteration (no vmcnt drain).
// Steady state: issue loads(t+2) -> ds_write(t+1 -> buf^1; its loads are a full iter old,
// compiler waits vmcnt(2)) -> compute+quant(t from buf[cur]) -> lds_barrier -> rotate.
// Wave w owns out-cols [64w,64w+64): half=w>>1 (u/v), hw=w&1. Byte layout per node:
// byte pos l15*8 + hw*4 + ntl <-> col hw*64 + ntl*16 + l15 (j<4 scale .x, j>=4 .y).
__global__ __launch_bounds__(256, 3) void node_uv(
    const float* __restrict__ h, const int4* __restrict__ blob,
    const float* __restrict__ b1,
    uint8_t* __restrict__ u8, uint8_t* __restrict__ v8,
    float* __restrict__ su, float* __restrict__ sv,   // [Nn][2]
    int Nn, int NT, int nblocks, int niter)
{
  __shared__ ushort As[2][2048];        // 2 x (16 rows x 128 cols bf16), XOR-swizzled; 8 KiB

  const int t0   = threadIdx.x;
  const int w    = t0 >> 6;
  const int l    = t0 & 63;
  const int l15  = l & 15;
  const int lg   = l >> 4;
  const int half = w >> 1;
  const int hw   = w & 1;

  bf16x8 bfrag[4][4];
#pragma unroll
  for (int ntl = 0; ntl < 4; ++ntl)
#pragma unroll
    for (int kk = 0; kk < 4; ++kk) {
      int4 x = blob[((half * 8 + hw * 4 + ntl) * 4 + kk) * 64 + l];
      bfrag[ntl][kk] = *reinterpret_cast<bf16x8*>(&x);
    }

  float b1r[4];
#pragma unroll
  for (int ntl = 0; ntl < 4; ++ntl)
    b1r[ntl] = half ? 0.f : b1[hw * 64 + ntl * 16 + l15];

  uint8_t* __restrict__ outp = half ? v8 : u8;
  float*   __restrict__ outs = half ? sv : su;

  const float4* h4 = (const float4*)h;

#define LOADT(T, g)                                            \
  {                                                            \
    const size_t hb = (size_t)(T) * 512;                       \
    _Pragma("unroll")                                          \
    for (int k = 0; k < 2; ++k) {                              \
      const int i = k * 256 + t0;                              \
      const int gr = (T) * 16 + (i >> 5);                      \
      (g)[k] = h4[gr < Nn ? hb + i : 0];                       \
    }                                                          \
  }

#define STORET(b, g)                                           \
  {                                                            \
    _Pragma("unroll")                                          \
    for (int k = 0; k < 2; ++k) {                              \
      const int i = k * 256 + t0, row = i >> 5, c = i & 31;    \
      ushort4 o;                                               \
      o.x = f2b((g)[k].x); o.y = f2b((g)[k].y);                \
      o.z = f2b((g)[k].z); o.w = f2b((g)[k].w);                \
      *(ushort4*)(&As[b][row * 128 + (((c >> 1) ^ (row & 7)) << 3) + (c & 1) * 4]) = o; \
    }                                                          \
  }

  int tc = blockIdx.x;
  int tn = tc + nblocks;
  float4 gC[2], gN[2], gNN[2];
  LOADT(tc, gC);
  LOADT(tn, gN);
  STORET(0, gC);
  lds_barrier();
  int cur = 0;

  for (int it = 0; it < niter; ++it) {
    const int tnn = tn + nblocks;
    LOADT(tnn, gNN);          // 2-ahead; stays in flight across the raw barrier
    STORET(cur ^ 1, gN);      // t+1 -> other buffer (compiler waits vmcnt(2) for gN)

    if (tc < NT) {
      f32x4 acc[4];
#pragma unroll
      for (int ntl = 0; ntl < 4; ++ntl) acc[ntl] = (f32x4){0.f, 0.f, 0.f, 0.f};

#pragma unroll
      for (int kk = 0; kk < 4; ++kk) {
        const int slot = (kk * 4 + lg) ^ (l15 & 7);
        int4 av = *(const int4*)(&As[cur][l15 * 128 + slot * 8]);
        const bf16x8 a = *reinterpret_cast<bf16x8*>(&av);
#pragma unroll
        for (int ntl = 0; ntl < 4; ++ntl)
          acc[ntl] = __builtin_amdgcn_mfma_f32_16x16x32_bf16(a, bfrag[ntl][kk], acc[ntl], 0, 0, 0);
      }

      const int n0 = tc * 16;
#pragma unroll
      for (int r = 0; r < 4; ++r) {
        float vals[4];
        float m = 1e-30f;
#pragma unroll
        for (int ntl = 0; ntl < 4; ++ntl) {
          const float x = acc[ntl][r] + b1r[ntl];
          vals[ntl] = x;
          m = fmaxf(m, fabsf(x));
        }
        m = fmaxf(m, __shfl_xor(m, 1));
        m = fmaxf(m, __shfl_xor(m, 2));
        m = fmaxf(m, __shfl_xor(m, 4));
        m = fmaxf(m, __shfl_xor(m, 8));
        const float inv = 127.0f * __builtin_amdgcn_rcpf(m);
        uint32_t pk = 0;
#pragma unroll
        for (int j = 0; j < 4; ++j) {
          const int q = (int)rintf(vals[j] * inv) + 128;        // 1..255
          pk |= (uint32_t)q << (8 * j);
        }
        const int node = n0 + lg * 4 + r;
        if (node < Nn) {
          *(uint32_t*)(outp + (size_t)node * 128 + l15 * 8 + hw * 4) = pk;
          if (l15 == 0) outs[node * 2 + hw] = m * (1.0f / 127.0f);
        }
      }
    }

    lds_barrier();            // buf[cur] reads done + buf[cur^1] writes visible; vmcnt live
    tc = tn; tn = tnn;
    gN[0] = gNN[0]; gN[1] = gNN[1];
    cur ^= 1;
  }
#undef LOADT
#undef STORET
}

// ---------------- Phase 2: score[e] = w2 . relu(s_u*(qu-128) + s_v*(qv-128)) + b2 ----------
// 16-lane group per edge, 4 edges per group-iteration.
__global__ __launch_bounds__(256) void edge_score_i8(
    const uint8_t* __restrict__ u8, const uint8_t* __restrict__ v8,
    const float* __restrict__ su, const float* __restrict__ sv,  // [Nn][2]
    const int* __restrict__ src, const int* __restrict__ dst,
    const float* __restrict__ w2, const float* __restrict__ b2p,
    float* __restrict__ out, int E)
{
  const int t  = threadIdx.x;
  const int l  = t & 63;
  const int q  = l & 15;
  const int lg = l >> 4;

  float w2r[8];
#pragma unroll
  for (int j = 0; j < 8; ++j) w2r[j] = w2[j * 16 + q];
  const float b2 = b2p[0];

  const int gw = blockIdx.x * 4 + (t >> 6);
  const int TW = gridDim.x * 4;
  const float2* su2 = (const float2*)su;
  const float2* sv2 = (const float2*)sv;

  for (int base = gw * 16; base < E; base += TW * 16) {
    int e[4]; bool ok[4];
    uint2 ug[4], vg[4];
    float2 ss[4], sd[4];
#pragma unroll
    for (int i = 0; i < 4; ++i) {
      e[i]  = base + i * 4 + lg;
      ok[i] = e[i] < E;
      const int eS = ok[i] ? e[i] : 0;
      const int s = src[eS];
      const int d = dst[eS];
      ug[i] = *(const uint2*)(u8 + (size_t)s * 128 + q * 8);
      vg[i] = *(const uint2*)(v8 + (size_t)d * 128 + q * 8);
      ss[i] = su2[s];
      sd[i] = sv2[d];
    }
#pragma unroll
    for (int i = 0; i < 4; ++i) {
      const uint32_t ux = ug[i].x, uy = ug[i].y;
      const uint32_t vx = vg[i].x, vy = vg[i].y;
      const float bse0 = -128.0f * (ss[i].x + sd[i].x);
      const float bse1 = -128.0f * (ss[i].y + sd[i].y);
      float acc = 0.f;
#pragma unroll
      for (int j = 0; j < 4; ++j) {
        const float cu = (float)((ux >> (8 * j)) & 0xffu);   // v_cvt_f32_ubyteN
        const float cv = (float)((vx >> (8 * j)) & 0xffu);
        float x = fmaf(cu, ss[i].x, fmaf(cv, sd[i].x, bse0));
        x = fmaxf(x, 0.f);
        acc = fmaf(x, w2r[j], acc);
      }
#pragma unroll
      for (int j = 0; j < 4; ++j) {
        const float cu = (float)((uy >> (8 * j)) & 0xffu);
        const float cv = (float)((vy >> (8 * j)) & 0xffu);
        float x = fmaf(cu, ss[i].y, fmaf(cv, sd[i].y, bse1));
        x = fmaxf(x, 0.f);
        acc = fmaf(x, w2r[4 + j], acc);
      }
      acc += __shfl_xor(acc, 1);
      acc += __shfl_xor(acc, 2);
      acc += __shfl_xor(acc, 4);
      acc += __shfl_xor(acc, 8);
      if (q == 0 && ok[i]) out[e[i]] = acc + b2;
    }
  }
}

extern "C" void kernel_launch(void* const* d_in, const int* in_sizes, int n_in,
                              void* d_out, int out_size, void* d_ws, size_t ws_size,
                              hipStream_t stream) {
  const float* h   = (const float*)d_in[0];
  const int*   src = (const int*)d_in[1];
  const int*   dst = (const int*)d_in[2];
  const float* W1  = (const float*)d_in[3];
  const float* b1  = (const float*)d_in[4];
  const float* w2  = (const float*)d_in[5];
  const float* b2  = (const float*)d_in[6];
  float* out = (float*)d_out;

  const int nh = in_sizes[0];
  const int Nn = nh / 128;
  const int E  = in_sizes[1];

  uint8_t* ws = (uint8_t*)d_ws;
  int4*  blob = (int4*)ws;                                          // 64 KiB
  size_t off  = 65536;
  float* su   = (float*)(ws + off);  off += (size_t)Nn * 8;
  off = (off + 511) & ~(size_t)511;
  float* sv   = (float*)(ws + off);  off += (size_t)Nn * 8;
  off = (off + 511) & ~(size_t)511;
  uint8_t* u8 = ws + off;            off += (size_t)Nn * 128;
  uint8_t* v8 = ws + off;

  hipLaunchKernelGGL(repack_W1, dim3(16), dim3(256), 0, stream, W1, blob);

  const int NT      = (Nn + 15) / 16;
  const int nblocks = 768;                     // 3 blocks/CU resident (persistent)
  const int niter   = (NT + nblocks - 1) / nblocks;
  hipLaunchKernelGGL(node_uv, dim3(nblocks), dim3(256), 0, stream,
                     h, blob, b1, u8, v8, su, sv, Nn, NT, nblocks, niter);

  hipLaunchKernelGGL(edge_score_i8, dim3(3072), dim3(256), 0, stream,
                     u8, v8, su, sv, src, dst, w2, b2, out, E);
}